// Round 1
// baseline (332.484 us; speedup 1.0000x reference)
//
#include <hip/hip_runtime.h>

#define L_LEN 8192
#define N_FFT 16384   // 2*L
#define NB    1024    // threads per block

// reverse 7 base-4 digits (14-bit index)
__device__ __forceinline__ int rev4_14(int m) {
    int r = 0;
#pragma unroll
    for (int d = 0; d < 7; ++d) { r = (r << 2) | (m & 3); m >>= 2; }
    return r;
}

__global__ __launch_bounds__(NB)
void fftconv_kernel(const float* __restrict__ xin,
                    const float* __restrict__ hin,
                    float* __restrict__ out)
{
    __shared__ float2 lds[N_FFT];   // 128 KiB

    const int row = blockIdx.x;
    const int tid = threadIdx.x;
    const float* xr = xin + (size_t)row * L_LEN;
    const float* hr = hin + (size_t)row * L_LEN;

    // ---- load z = x + i*h, zero-pad to N ----
#pragma unroll
    for (int i = tid; i < L_LEN / 4; i += NB) {
        float4 xv = ((const float4*)xr)[i];
        float4 hv = ((const float4*)hr)[i];
        int j = i * 4;
        lds[j + 0] = make_float2(xv.x, hv.x);
        lds[j + 1] = make_float2(xv.y, hv.y);
        lds[j + 2] = make_float2(xv.z, hv.z);
        lds[j + 3] = make_float2(xv.w, hv.w);
    }
#pragma unroll
    for (int j = L_LEN + tid; j < N_FFT; j += NB)
        lds[j] = make_float2(0.f, 0.f);
    __syncthreads();

    // ---- forward radix-4 DIF: natural in -> base-4 digit-reversed out ----
#pragma unroll
    for (int s = 0; s < 7; ++s) {
        const int shift = 12 - 2 * s;        // log2(q), q = n_s/4
        const int q = 1 << shift;
        const float ang = -6.283185307179586f / (float)(q << 2);  // -2pi/n_s
        for (int w = tid; w < N_FFT / 4; w += NB) {
            const int t = w & (q - 1);
            const int g = w >> shift;
            const int i0 = (g << (shift + 2)) + t;
            const int i1 = i0 + q, i2 = i0 + 2 * q, i3 = i0 + 3 * q;
            float2 x0 = lds[i0], x1 = lds[i1], x2 = lds[i2], x3 = lds[i3];

            float Ar = x0.x + x2.x, Ai = x0.y + x2.y;
            float Br = x0.x - x2.x, Bi = x0.y - x2.y;
            float Cr = x1.x + x3.x, Ci = x1.y + x3.y;
            float Dr = x1.x - x3.x, Di = x1.y - x3.y;

            float sn, cs;
            __sincosf(ang * (float)t, &sn, &cs);
            float w1r = cs, w1i = sn;
            float w2r = w1r * w1r - w1i * w1i, w2i = 2.f * w1r * w1i;
            float w3r = w2r * w1r - w2i * w1i, w3i = w2r * w1i + w2i * w1r;

            // g0 = A+C ; g1 = (B - iD) W^t ; g2 = (A-C) W^2t ; g3 = (B + iD) W^3t
            float g1r = Br + Di, g1i = Bi - Dr;
            float g2r = Ar - Cr, g2i = Ai - Ci;
            float g3r = Br - Di, g3i = Bi + Dr;

            lds[i0] = make_float2(Ar + Cr, Ai + Ci);
            lds[i1] = make_float2(g1r * w1r - g1i * w1i, g1r * w1i + g1i * w1r);
            lds[i2] = make_float2(g2r * w2r - g2i * w2i, g2r * w2i + g2i * w2r);
            lds[i3] = make_float2(g3r * w3r - g3i * w3i, g3r * w3i + g3i * w3r);
        }
        __syncthreads();
    }

    // ---- pointwise: split Z -> X,H (Hermitian), Y = X*H, in digit-reversed order ----
    for (int m = tid; m < L_LEN; m += NB) {
        if (m == 0) {
            // bin 0 at pos rev4(0)=0 ; bin N/2 at pos rev4(8192)=2 ; both self-paired
            float2 z0 = lds[0];
            lds[0] = make_float2(z0.x * z0.y, 0.f);
            float2 zn = lds[2];
            lds[2] = make_float2(zn.x * zn.y, 0.f);
        } else {
            const int j  = rev4_14(m);
            const int j2 = rev4_14(N_FFT - m);
            float2 zm = lds[j], zr = lds[j2];
            float Xr = 0.5f * (zm.x + zr.x), Xi = 0.5f * (zm.y - zr.y);
            float Hr = 0.5f * (zm.y + zr.y), Hi = 0.5f * (zr.x - zm.x);
            float Yr = Xr * Hr - Xi * Hi;
            float Yi = Xr * Hi + Xi * Hr;
            lds[j]  = make_float2(Yr,  Yi);
            lds[j2] = make_float2(Yr, -Yi);   // Y[N-m] = conj(Y[m])
        }
    }
    __syncthreads();

    // ---- inverse radix-4 DIT: digit-reversed in -> natural out (unscaled) ----
#pragma unroll
    for (int s = 0; s < 7; ++s) {
        const int shift = 2 * s;             // log2(q), q = 4^s
        const int q = 1 << shift;
        const float ang = 6.283185307179586f / (float)(q << 2);   // +2pi/n_s
        for (int w = tid; w < N_FFT / 4; w += NB) {
            const int t = w & (q - 1);
            const int g = w >> shift;
            const int i0 = (g << (shift + 2)) + t;
            const int i1 = i0 + q, i2 = i0 + 2 * q, i3 = i0 + 3 * q;
            float2 a0 = lds[i0], x1 = lds[i1], x2 = lds[i2], x3 = lds[i3];

            float sn, cs;
            __sincosf(ang * (float)t, &sn, &cs);
            float w1r = cs, w1i = sn;
            float w2r = w1r * w1r - w1i * w1i, w2i = 2.f * w1r * w1i;
            float w3r = w2r * w1r - w2i * w1i, w3i = w2r * w1i + w2i * w1r;

            float a1r = x1.x * w1r - x1.y * w1i, a1i = x1.x * w1i + x1.y * w1r;
            float a2r = x2.x * w2r - x2.y * w2i, a2i = x2.x * w2i + x2.y * w2r;
            float a3r = x3.x * w3r - x3.y * w3i, a3i = x3.x * w3i + x3.y * w3r;

            float Er = a0.x + a2r, Ei = a0.y + a2i;   // a0 + a2
            float Fr = a0.x - a2r, Fi = a0.y - a2i;   // a0 - a2
            float Gr = a1r + a3r,  Gi = a1i + a3i;    // a1 + a3
            float Kr = a1r - a3r,  Ki = a1i - a3i;    // a1 - a3

            lds[i0] = make_float2(Er + Gr, Ei + Gi);  // y0 = E+G
            lds[i1] = make_float2(Fr - Ki, Fi + Kr);  // y1 = F+iK
            lds[i2] = make_float2(Er - Gr, Ei - Gi);  // y2 = E-G
            lds[i3] = make_float2(Fr + Ki, Fi - Kr);  // y3 = F-iK
        }
        __syncthreads();
    }

    // ---- store first L real parts, scaled by 1/N^2 (net torch-forward 1/n) ----
    const float scale = 1.0f / ((float)N_FFT * (float)N_FFT);   // 2^-28
    float* orow = out + (size_t)row * L_LEN;
#pragma unroll
    for (int i = tid; i < L_LEN / 4; i += NB) {
        int j = 4 * i;
        float4 o;
        o.x = lds[j + 0].x * scale;
        o.y = lds[j + 1].x * scale;
        o.z = lds[j + 2].x * scale;
        o.w = lds[j + 3].x * scale;
        ((float4*)orow)[i] = o;
    }
}

extern "C" void kernel_launch(void* const* d_in, const int* in_sizes, int n_in,
                              void* d_out, int out_size, void* d_ws, size_t ws_size,
                              hipStream_t stream) {
    const float* x = (const float*)d_in[0];
    const float* h = (const float*)d_in[1];
    float* out = (float*)d_out;
    const int rows = in_sizes[0] / L_LEN;   // 2048
    fftconv_kernel<<<dim3(rows), dim3(NB), 0, stream>>>(x, h, out);
}

// Round 2
// 248.539 us; speedup vs baseline: 1.3378x; 1.3378x over previous
//
#include <hip/hip_runtime.h>

#define L_LEN 8192
#define N_FFT 16384   // 2*L
#define NB    1024    // threads per block

// bijective LDS index swizzle: spreads bank-row slot (i%16 for float2)
// with all higher index bits, killing stride-conflicts in every phase.
__device__ __forceinline__ int swz(int i) {
    return i ^ ((((i) >> 4) ^ ((i) >> 8) ^ ((i) >> 12)) & 15);
}

// reverse 7 base-4 digits (14-bit index)
__device__ __forceinline__ int rev4_14(int m) {
    int r = 0;
#pragma unroll
    for (int d = 0; d < 7; ++d) { r = (r << 2) | (m & 3); m >>= 2; }
    return r;
}

__global__ __launch_bounds__(NB)
void fftconv_kernel(const float* __restrict__ xin,
                    const float* __restrict__ hin,
                    float* __restrict__ out)
{
    __shared__ float2 lds[N_FFT];   // 128 KiB

    const int row = blockIdx.x;
    const int tid = threadIdx.x;
    const float* xr = xin + (size_t)row * L_LEN;
    const float* hr = hin + (size_t)row * L_LEN;

    // ---- load z = x + i*h, zero-pad to N ----
#pragma unroll
    for (int i = tid; i < L_LEN / 4; i += NB) {
        float4 xv = ((const float4*)xr)[i];
        float4 hv = ((const float4*)hr)[i];
        int j = i * 4;
        lds[swz(j + 0)] = make_float2(xv.x, hv.x);
        lds[swz(j + 1)] = make_float2(xv.y, hv.y);
        lds[swz(j + 2)] = make_float2(xv.z, hv.z);
        lds[swz(j + 3)] = make_float2(xv.w, hv.w);
    }
#pragma unroll
    for (int j = L_LEN + tid; j < N_FFT; j += NB)
        lds[swz(j)] = make_float2(0.f, 0.f);
    __syncthreads();

    // ---- forward radix-4 DIF: natural in -> base-4 digit-reversed out ----
#pragma unroll
    for (int s = 0; s < 7; ++s) {
        const int shift = 12 - 2 * s;        // log2(q), q = n_s/4
        const int q = 1 << shift;
        const float ang = -6.283185307179586f / (float)(q << 2);  // -2pi/n_s
        for (int w = tid; w < N_FFT / 4; w += NB) {
            const int t = w & (q - 1);
            const int g = w >> shift;
            const int i0 = (g << (shift + 2)) + t;
            const int s0 = swz(i0), s1 = swz(i0 + q), s2 = swz(i0 + 2 * q), s3 = swz(i0 + 3 * q);
            float2 x0 = lds[s0], x1 = lds[s1], x2 = lds[s2], x3 = lds[s3];

            float Ar = x0.x + x2.x, Ai = x0.y + x2.y;
            float Br = x0.x - x2.x, Bi = x0.y - x2.y;
            float Cr = x1.x + x3.x, Ci = x1.y + x3.y;
            float Dr = x1.x - x3.x, Di = x1.y - x3.y;

            float sn, cs;
            __sincosf(ang * (float)t, &sn, &cs);
            float w1r = cs, w1i = sn;
            float w2r = w1r * w1r - w1i * w1i, w2i = 2.f * w1r * w1i;
            float w3r = w2r * w1r - w2i * w1i, w3i = w2r * w1i + w2i * w1r;

            // g0 = A+C ; g1 = (B - iD) W^t ; g2 = (A-C) W^2t ; g3 = (B + iD) W^3t
            float g1r = Br + Di, g1i = Bi - Dr;
            float g2r = Ar - Cr, g2i = Ai - Ci;
            float g3r = Br - Di, g3i = Bi + Dr;

            lds[s0] = make_float2(Ar + Cr, Ai + Ci);
            lds[s1] = make_float2(g1r * w1r - g1i * w1i, g1r * w1i + g1i * w1r);
            lds[s2] = make_float2(g2r * w2r - g2i * w2i, g2r * w2i + g2i * w2r);
            lds[s3] = make_float2(g3r * w3r - g3i * w3i, g3r * w3i + g3i * w3r);
        }
        __syncthreads();
    }

    // ---- pointwise: split Z -> X,H (Hermitian), Y = X*H, in digit-reversed order ----
    for (int m = tid; m < L_LEN; m += NB) {
        if (m == 0) {
            // bin 0 at pos rev4(0)=0 ; bin N/2 at pos rev4(8192)=2 ; both self-paired
            float2 z0 = lds[swz(0)];
            lds[swz(0)] = make_float2(z0.x * z0.y, 0.f);
            float2 zn = lds[swz(2)];
            lds[swz(2)] = make_float2(zn.x * zn.y, 0.f);
        } else {
            const int j  = swz(rev4_14(m));
            const int j2 = swz(rev4_14(N_FFT - m));
            float2 zm = lds[j], zr = lds[j2];
            float Xr = 0.5f * (zm.x + zr.x), Xi = 0.5f * (zm.y - zr.y);
            float Hr = 0.5f * (zm.y + zr.y), Hi = 0.5f * (zr.x - zm.x);
            float Yr = Xr * Hr - Xi * Hi;
            float Yi = Xr * Hi + Xi * Hr;
            lds[j]  = make_float2(Yr,  Yi);
            lds[j2] = make_float2(Yr, -Yi);   // Y[N-m] = conj(Y[m])
        }
    }
    __syncthreads();

    // ---- inverse radix-4 DIT: digit-reversed in -> natural out (unscaled) ----
#pragma unroll
    for (int s = 0; s < 7; ++s) {
        const int shift = 2 * s;             // log2(q), q = 4^s
        const int q = 1 << shift;
        const float ang = 6.283185307179586f / (float)(q << 2);   // +2pi/n_s
        for (int w = tid; w < N_FFT / 4; w += NB) {
            const int t = w & (q - 1);
            const int g = w >> shift;
            const int i0 = (g << (shift + 2)) + t;
            const int s0 = swz(i0), s1 = swz(i0 + q), s2 = swz(i0 + 2 * q), s3 = swz(i0 + 3 * q);
            float2 a0 = lds[s0], x1 = lds[s1], x2 = lds[s2], x3 = lds[s3];

            float sn, cs;
            __sincosf(ang * (float)t, &sn, &cs);
            float w1r = cs, w1i = sn;
            float w2r = w1r * w1r - w1i * w1i, w2i = 2.f * w1r * w1i;
            float w3r = w2r * w1r - w2i * w1i, w3i = w2r * w1i + w2i * w1r;

            float a1r = x1.x * w1r - x1.y * w1i, a1i = x1.x * w1i + x1.y * w1r;
            float a2r = x2.x * w2r - x2.y * w2i, a2i = x2.x * w2i + x2.y * w2r;
            float a3r = x3.x * w3r - x3.y * w3i, a3i = x3.x * w3i + x3.y * w3r;

            float Er = a0.x + a2r, Ei = a0.y + a2i;   // a0 + a2
            float Fr = a0.x - a2r, Fi = a0.y - a2i;   // a0 - a2
            float Gr = a1r + a3r,  Gi = a1i + a3i;    // a1 + a3
            float Kr = a1r - a3r,  Ki = a1i - a3i;    // a1 - a3

            lds[s0] = make_float2(Er + Gr, Ei + Gi);  // y0 = E+G
            lds[s1] = make_float2(Fr - Ki, Fi + Kr);  // y1 = F+iK
            lds[s2] = make_float2(Er - Gr, Ei - Gi);  // y2 = E-G
            lds[s3] = make_float2(Fr + Ki, Fi - Kr);  // y3 = F-iK
        }
        __syncthreads();
    }

    // ---- store first L real parts, scaled by 1/N^2 (net torch-forward 1/n) ----
    const float scale = 1.0f / ((float)N_FFT * (float)N_FFT);   // 2^-28
    float* orow = out + (size_t)row * L_LEN;
#pragma unroll
    for (int i = tid; i < L_LEN / 4; i += NB) {
        int j = 4 * i;
        float4 o;
        o.x = lds[swz(j + 0)].x * scale;
        o.y = lds[swz(j + 1)].x * scale;
        o.z = lds[swz(j + 2)].x * scale;
        o.w = lds[swz(j + 3)].x * scale;
        ((float4*)orow)[i] = o;
    }
}

extern "C" void kernel_launch(void* const* d_in, const int* in_sizes, int n_in,
                              void* d_out, int out_size, void* d_ws, size_t ws_size,
                              hipStream_t stream) {
    const float* x = (const float*)d_in[0];
    const float* h = (const float*)d_in[1];
    float* out = (float*)d_out;
    const int rows = in_sizes[0] / L_LEN;   // 2048
    fftconv_kernel<<<dim3(rows), dim3(NB), 0, stream>>>(x, h, out);
}

// Round 3
// 240.831 us; speedup vs baseline: 1.3806x; 1.0320x over previous
//
#include <hip/hip_runtime.h>

#define L_LEN 8192
#define N_FFT 16384   // 2*L
#define NB    1024    // threads per block; each thread owns 16 points per pass

// bijective LDS index swizzle: spreads bank-row slot (i%16 for float2)
// with all higher index bits, killing stride-conflicts in every phase.
__device__ __forceinline__ int swz(int i) {
    return i ^ ((((i) >> 4) ^ ((i) >> 8) ^ ((i) >> 12)) & 15);
}

// reverse 6 base-4 digits (12-bit index) — quad index <-> low 6 digits of bin
__device__ __forceinline__ int rev4_12(int m) {
    int r = 0;
#pragma unroll
    for (int d = 0; d < 6; ++d) { r = (r << 2) | (m & 3); m >>= 2; }
    return r;
}

__device__ __forceinline__ float2 cmul(float2 a, float cr, float ci) {
    return make_float2(a.x * cr - a.y * ci, a.x * ci + a.y * cr);
}

// DIF radix-4 butterfly with twiddle W = (c,s) = e^{i*ang*t} (ang negative).
// x_k at offsets k*q; outputs y0=A+C, y1=(B-iD)W, y2=(A-C)W^2, y3=(B+iD)W^3.
__device__ __forceinline__ void bfly_dif_w(float2& x0, float2& x1, float2& x2, float2& x3,
                                           float c, float s) {
    float Ar = x0.x + x2.x, Ai = x0.y + x2.y;
    float Br = x0.x - x2.x, Bi = x0.y - x2.y;
    float Cr = x1.x + x3.x, Ci = x1.y + x3.y;
    float Dr = x1.x - x3.x, Di = x1.y - x3.y;
    float w2r = c * c - s * s, w2i = 2.f * c * s;
    float w3r = w2r * c - w2i * s, w3i = w2r * s + w2i * c;
    x0 = make_float2(Ar + Cr, Ai + Ci);
    x1 = cmul(make_float2(Br + Di, Bi - Dr), c, s);
    x2 = cmul(make_float2(Ar - Cr, Ai - Ci), w2r, w2i);
    x3 = cmul(make_float2(Br - Di, Bi + Dr), w3r, w3i);
}

// DIT radix-4 butterfly: twiddle-multiply inputs then combine.
__device__ __forceinline__ void bfly_dit_w(float2& x0, float2& x1, float2& x2, float2& x3,
                                           float c, float s) {
    float w2r = c * c - s * s, w2i = 2.f * c * s;
    float w3r = w2r * c - w2i * s, w3i = w2r * s + w2i * c;
    float2 a1 = cmul(x1, c, s);
    float2 a2 = cmul(x2, w2r, w2i);
    float2 a3 = cmul(x3, w3r, w3i);
    float Er = x0.x + a2.x, Ei = x0.y + a2.y;
    float Fr = x0.x - a2.x, Fi = x0.y - a2.y;
    float Gr = a1.x + a3.x, Gi = a1.y + a3.y;
    float Kr = a1.x - a3.x, Ki = a1.y - a3.y;
    x0 = make_float2(Er + Gr, Ei + Gi);
    x1 = make_float2(Fr - Ki, Fi + Kr);
    x2 = make_float2(Er - Gr, Ei - Gi);
    x3 = make_float2(Fr + Ki, Fi - Kr);
}

// twiddle-free DIF (t=0)
__device__ __forceinline__ void bfly_dif_1(float2* z) {
    float Ar = z[0].x + z[2].x, Ai = z[0].y + z[2].y;
    float Br = z[0].x - z[2].x, Bi = z[0].y - z[2].y;
    float Cr = z[1].x + z[3].x, Ci = z[1].y + z[3].y;
    float Dr = z[1].x - z[3].x, Di = z[1].y - z[3].y;
    z[0] = make_float2(Ar + Cr, Ai + Ci);
    z[1] = make_float2(Br + Di, Bi - Dr);
    z[2] = make_float2(Ar - Cr, Ai - Ci);
    z[3] = make_float2(Br - Di, Bi + Dr);
}

// twiddle-free DIT (t=0)
__device__ __forceinline__ void bfly_dit_1(float2* z) {
    float Er = z[0].x + z[2].x, Ei = z[0].y + z[2].y;
    float Fr = z[0].x - z[2].x, Fi = z[0].y - z[2].y;
    float Gr = z[1].x + z[3].x, Gi = z[1].y + z[3].y;
    float Kr = z[1].x - z[3].x, Ki = z[1].y - z[3].y;
    z[0] = make_float2(Er + Gr, Ei + Gi);
    z[1] = make_float2(Fr - Ki, Fi + Kr);
    z[2] = make_float2(Er - Gr, Ei - Gi);
    z[3] = make_float2(Fr + Ki, Fi - Kr);
}

// pointwise Y = X*H from Z[m], Z[N-m] of the packed z = x + i*h transform
__device__ __forceinline__ void pointwise_pair(float2& Zm, float2& Zr) {
    float Xr = 0.5f * (Zm.x + Zr.x), Xi = 0.5f * (Zm.y - Zr.y);
    float Hr = 0.5f * (Zm.y + Zr.y), Hi = 0.5f * (Zr.x - Zm.x);
    float Yr = Xr * Hr - Xi * Hi;
    float Yi = Xr * Hi + Xi * Hr;
    Zm = make_float2(Yr, Yi);
    Zr = make_float2(Yr, -Yi);
}

// Fused forward DIF pair: stage q=QA then q=QA/4, one LDS round-trip.
template<int QA>
__device__ __forceinline__ void fwd_pair(float2* lds, int tid) {
    constexpr int QB = QA / 4;
    const int g = tid / QB;
    const int u = tid % QB;
    const int base = g * (4 * QA) + u;
    float2 r[4][4];
#pragma unroll
    for (int jA = 0; jA < 4; ++jA)
#pragma unroll
        for (int jB = 0; jB < 4; ++jB)
            r[jA][jB] = lds[swz(base + jA * QA + jB * QB)];

    const float angA = -6.283185307179586f / (float)(4 * QA);
#pragma unroll
    for (int jB = 0; jB < 4; ++jB) {
        float sn, cs;
        __sincosf(angA * (float)(u + jB * QB), &sn, &cs);
        bfly_dif_w(r[0][jB], r[1][jB], r[2][jB], r[3][jB], cs, sn);
    }
    const float angB = -6.283185307179586f / (float)(4 * QB);
    float snB, csB;
    __sincosf(angB * (float)u, &snB, &csB);
#pragma unroll
    for (int jA = 0; jA < 4; ++jA)
        bfly_dif_w(r[jA][0], r[jA][1], r[jA][2], r[jA][3], csB, snB);

#pragma unroll
    for (int jA = 0; jA < 4; ++jA)
#pragma unroll
        for (int jB = 0; jB < 4; ++jB)
            lds[swz(base + jA * QA + jB * QB)] = r[jA][jB];
}

// Fused inverse DIT pair: stage q=QA then q=4*QA, one LDS round-trip.
template<int QA>
__device__ __forceinline__ void inv_pair(float2* lds, int tid) {
    constexpr int QB = 4 * QA;
    const int G = tid / QA;
    const int u = tid % QA;
    const int base = G * (16 * QA) + u;
    float2 r[4][4];
#pragma unroll
    for (int jA = 0; jA < 4; ++jA)
#pragma unroll
        for (int jB = 0; jB < 4; ++jB)
            r[jA][jB] = lds[swz(base + jA * QA + jB * QB)];

    const float angA = 6.283185307179586f / (float)(4 * QA);
    float snA, csA;
    __sincosf(angA * (float)u, &snA, &csA);
#pragma unroll
    for (int jB = 0; jB < 4; ++jB)
        bfly_dit_w(r[0][jB], r[1][jB], r[2][jB], r[3][jB], csA, snA);

    const float angB = 6.283185307179586f / (float)(4 * QB);
#pragma unroll
    for (int jA = 0; jA < 4; ++jA) {
        float sn, cs;
        __sincosf(angB * (float)(u + jA * QA), &sn, &cs);
        bfly_dit_w(r[jA][0], r[jA][1], r[jA][2], r[jA][3], cs, sn);
    }

#pragma unroll
    for (int jA = 0; jA < 4; ++jA)
#pragma unroll
        for (int jB = 0; jB < 4; ++jB)
            lds[swz(base + jA * QA + jB * QB)] = r[jA][jB];
}

__global__ __launch_bounds__(NB)
void fftconv_kernel(const float* __restrict__ xin,
                    const float* __restrict__ hin,
                    float* __restrict__ out)
{
    __shared__ float2 lds[N_FFT];   // 128 KiB

    const int row = blockIdx.x;
    const int tid = threadIdx.x;
    const float* xr = xin + (size_t)row * L_LEN;
    const float* hr = hin + (size_t)row * L_LEN;

    // ---- load z = x + i*h, zero-pad to N ----
#pragma unroll
    for (int i = tid; i < L_LEN / 4; i += NB) {
        float4 xv = ((const float4*)xr)[i];
        float4 hv = ((const float4*)hr)[i];
        int j = i * 4;
        lds[swz(j + 0)] = make_float2(xv.x, hv.x);
        lds[swz(j + 1)] = make_float2(xv.y, hv.y);
        lds[swz(j + 2)] = make_float2(xv.z, hv.z);
        lds[swz(j + 3)] = make_float2(xv.w, hv.w);
    }
#pragma unroll
    for (int j = L_LEN + tid; j < N_FFT; j += NB)
        lds[swz(j)] = make_float2(0.f, 0.f);
    __syncthreads();

    // ---- forward: fused radix-16 passes (q = 4096&1024, 256&64, 16&4) ----
    fwd_pair<4096>(lds, tid); __syncthreads();
    fwd_pair<256>(lds, tid);  __syncthreads();
    fwd_pair<16>(lds, tid);   __syncthreads();

    // ---- combo pass: fwd q=1 + Hermitian pointwise + inv q=1, in registers ----
    // Quad at positions 4a..4a+3 (a = rev6(b)) holds bins k*4096 + b.
    // Quad b pairs with quad 4096-b; entry k pairs with partner entry 3-k.
#pragma unroll
    for (int iter = 0; iter < 2; ++iter) {
        const int p = tid + iter * NB;          // p in [0, 2048)
        if (p == 0) {
            // quad a=0 (b=0): bins {0,4096,8192,12288}
            float2 z[4];
#pragma unroll
            for (int k = 0; k < 4; ++k) z[k] = lds[swz(0 + k)];
            bfly_dif_1(z);
            z[0] = make_float2(z[0].x * z[0].y, 0.f);   // bin 0
            z[2] = make_float2(z[2].x * z[2].y, 0.f);   // bin N/2
            pointwise_pair(z[1], z[3]);                 // 4096 <-> 12288
            bfly_dit_1(z);
#pragma unroll
            for (int k = 0; k < 4; ++k) lds[swz(0 + k)] = z[k];
            // quad a=2 (b=2048): bins k*4096+2048; pairs (0,3),(1,2)
            float2 w[4];
#pragma unroll
            for (int k = 0; k < 4; ++k) w[k] = lds[swz(8 + k)];
            bfly_dif_1(w);
            pointwise_pair(w[0], w[3]);
            pointwise_pair(w[1], w[2]);
            bfly_dit_1(w);
#pragma unroll
            for (int k = 0; k < 4; ++k) lds[swz(8 + k)] = w[k];
        } else {
            const int aA = rev4_12(p);
            const int aB = rev4_12(4096 - p);
            float2 A[4], B[4];
#pragma unroll
            for (int k = 0; k < 4; ++k) A[k] = lds[swz(4 * aA + k)];
#pragma unroll
            for (int k = 0; k < 4; ++k) B[k] = lds[swz(4 * aB + k)];
            bfly_dif_1(A);
            bfly_dif_1(B);
            pointwise_pair(A[0], B[3]);
            pointwise_pair(A[1], B[2]);
            pointwise_pair(A[2], B[1]);
            pointwise_pair(A[3], B[0]);
            bfly_dit_1(A);
            bfly_dit_1(B);
#pragma unroll
            for (int k = 0; k < 4; ++k) lds[swz(4 * aA + k)] = A[k];
#pragma unroll
            for (int k = 0; k < 4; ++k) lds[swz(4 * aB + k)] = B[k];
        }
    }
    __syncthreads();

    // ---- inverse: fused radix-16 passes (q = 4&16, 64&256, 1024&4096) ----
    inv_pair<4>(lds, tid);    __syncthreads();
    inv_pair<64>(lds, tid);   __syncthreads();
    inv_pair<1024>(lds, tid); __syncthreads();

    // ---- store first L real parts, scaled by 1/N^2 (net torch-forward 1/n) ----
    const float scale = 1.0f / ((float)N_FFT * (float)N_FFT);   // 2^-28
    float* orow = out + (size_t)row * L_LEN;
#pragma unroll
    for (int i = tid; i < L_LEN / 4; i += NB) {
        int j = 4 * i;
        float4 o;
        o.x = lds[swz(j + 0)].x * scale;
        o.y = lds[swz(j + 1)].x * scale;
        o.z = lds[swz(j + 2)].x * scale;
        o.w = lds[swz(j + 3)].x * scale;
        ((float4*)orow)[i] = o;
    }
}

extern "C" void kernel_launch(void* const* d_in, const int* in_sizes, int n_in,
                              void* d_out, int out_size, void* d_ws, size_t ws_size,
                              hipStream_t stream) {
    const float* x = (const float*)d_in[0];
    const float* h = (const float*)d_in[1];
    float* out = (float*)d_out;
    const int rows = in_sizes[0] / L_LEN;   // 2048
    fftconv_kernel<<<dim3(rows), dim3(NB), 0, stream>>>(x, h, out);
}

// Round 4
// 211.481 us; speedup vs baseline: 1.5722x; 1.1388x over previous
//
#include <hip/hip_runtime.h>

#define L_LEN 8192
#define N_FFT 16384   // 2*L
#define NB    1024    // threads per block; each thread owns 16 points per pass

// LDS already caps occupancy at 1 block/CU = 4 waves/EU; tell the compiler so
// it can use up to 128 VGPRs instead of spilling at its default 64-VGPR target.
#define LB __launch_bounds__(NB, 4)

// bijective LDS index swizzle: spreads bank-row slot (i%16 for float2)
// with all higher index bits, killing stride-conflicts in every phase.
__device__ __forceinline__ int swz(int i) {
    return i ^ ((((i) >> 4) ^ ((i) >> 8) ^ ((i) >> 12)) & 15);
}

// reverse 6 base-4 digits (12-bit index) — quad index <-> low 6 digits of bin
__device__ __forceinline__ int rev4_12(int m) {
    int r = 0;
#pragma unroll
    for (int d = 0; d < 6; ++d) { r = (r << 2) | (m & 3); m >>= 2; }
    return r;
}

// cos/sin of 2*pi*j/16, j=0..3 (compile-time twiddle ladder constants)
__device__ __constant__ float C16[4] = {1.0f, 0.92387953251128674f, 0.70710678118654752f, 0.38268343236508977f};
__device__ __constant__ float S16[4] = {0.0f, 0.38268343236508977f, 0.70710678118654752f, 0.92387953251128674f};

__device__ __forceinline__ float2 cmul(float2 a, float cr, float ci) {
    return make_float2(a.x * cr - a.y * ci, a.x * ci + a.y * cr);
}

// DIF radix-4 butterfly with twiddle W = (c,s) (negative-angle convention).
__device__ __forceinline__ void bfly_dif_w(float2& x0, float2& x1, float2& x2, float2& x3,
                                           float c, float s) {
    float Ar = x0.x + x2.x, Ai = x0.y + x2.y;
    float Br = x0.x - x2.x, Bi = x0.y - x2.y;
    float Cr = x1.x + x3.x, Ci = x1.y + x3.y;
    float Dr = x1.x - x3.x, Di = x1.y - x3.y;
    float w2r = c * c - s * s, w2i = 2.f * c * s;
    float w3r = w2r * c - w2i * s, w3i = w2r * s + w2i * c;
    x0 = make_float2(Ar + Cr, Ai + Ci);
    x1 = cmul(make_float2(Br + Di, Bi - Dr), c, s);
    x2 = cmul(make_float2(Ar - Cr, Ai - Ci), w2r, w2i);
    x3 = cmul(make_float2(Br - Di, Bi + Dr), w3r, w3i);
}

// DIT radix-4 butterfly: twiddle-multiply inputs then combine.
__device__ __forceinline__ void bfly_dit_w(float2& x0, float2& x1, float2& x2, float2& x3,
                                           float c, float s) {
    float w2r = c * c - s * s, w2i = 2.f * c * s;
    float w3r = w2r * c - w2i * s, w3i = w2r * s + w2i * c;
    float2 a1 = cmul(x1, c, s);
    float2 a2 = cmul(x2, w2r, w2i);
    float2 a3 = cmul(x3, w3r, w3i);
    float Er = x0.x + a2.x, Ei = x0.y + a2.y;
    float Fr = x0.x - a2.x, Fi = x0.y - a2.y;
    float Gr = a1.x + a3.x, Gi = a1.y + a3.y;
    float Kr = a1.x - a3.x, Ki = a1.y - a3.y;
    x0 = make_float2(Er + Gr, Ei + Gi);
    x1 = make_float2(Fr - Ki, Fi + Kr);
    x2 = make_float2(Er - Gr, Ei - Gi);
    x3 = make_float2(Fr + Ki, Fi - Kr);
}

// twiddle-free DIF (t=0)
__device__ __forceinline__ void bfly_dif_1(float2* z) {
    float Ar = z[0].x + z[2].x, Ai = z[0].y + z[2].y;
    float Br = z[0].x - z[2].x, Bi = z[0].y - z[2].y;
    float Cr = z[1].x + z[3].x, Ci = z[1].y + z[3].y;
    float Dr = z[1].x - z[3].x, Di = z[1].y - z[3].y;
    z[0] = make_float2(Ar + Cr, Ai + Ci);
    z[1] = make_float2(Br + Di, Bi - Dr);
    z[2] = make_float2(Ar - Cr, Ai - Ci);
    z[3] = make_float2(Br - Di, Bi + Dr);
}

// twiddle-free DIT (t=0)
__device__ __forceinline__ void bfly_dit_1(float2* z) {
    float Er = z[0].x + z[2].x, Ei = z[0].y + z[2].y;
    float Fr = z[0].x - z[2].x, Fi = z[0].y - z[2].y;
    float Gr = z[1].x + z[3].x, Gi = z[1].y + z[3].y;
    float Kr = z[1].x - z[3].x, Ki = z[1].y - z[3].y;
    z[0] = make_float2(Er + Gr, Ei + Gi);
    z[1] = make_float2(Fr - Ki, Fi + Kr);
    z[2] = make_float2(Er - Gr, Ei - Gi);
    z[3] = make_float2(Fr + Ki, Fi - Kr);
}

// pointwise Y = X*H from Z[m], Z[N-m] of the packed z = x + i*h transform
__device__ __forceinline__ void pointwise_pair(float2& Zm, float2& Zr) {
    float Xr = 0.5f * (Zm.x + Zr.x), Xi = 0.5f * (Zm.y - Zr.y);
    float Hr = 0.5f * (Zm.y + Zr.y), Hi = 0.5f * (Zr.x - Zm.x);
    float Yr = Xr * Hr - Xi * Hi;
    float Yi = Xr * Hi + Xi * Hr;
    Zm = make_float2(Yr, Yi);
    Zr = make_float2(Yr, -Yi);
}

// Fused forward DIF pair: stage q=QA then q=QA/4, one LDS round-trip.
template<int QA>
__device__ __forceinline__ void fwd_pair(float2* lds, int tid) {
    constexpr int QB = QA / 4;
    const int g = tid / QB;
    const int u = tid % QB;
    const int base = g * (4 * QA) + u;
    float2 r[4][4];
#pragma unroll
    for (int jA = 0; jA < 4; ++jA)
#pragma unroll
        for (int jB = 0; jB < 4; ++jB)
            r[jA][jB] = lds[swz(base + jA * QA + jB * QB)];

    // Stage A twiddle for column jB is W^(u + jB*QB) = W^u * e^{-2pi*i*jB/16}
    const float angA = -6.283185307179586f / (float)(4 * QA);
    float snU, csU;
    __sincosf(angA * (float)u, &snU, &csU);
#pragma unroll
    for (int jB = 0; jB < 4; ++jB) {
        float c = csU * C16[jB] + snU * S16[jB];
        float s = snU * C16[jB] - csU * S16[jB];
        bfly_dif_w(r[0][jB], r[1][jB], r[2][jB], r[3][jB], c, s);
    }
    const float angB = -6.283185307179586f / (float)(4 * QB);
    float snB, csB;
    __sincosf(angB * (float)u, &snB, &csB);
#pragma unroll
    for (int jA = 0; jA < 4; ++jA)
        bfly_dif_w(r[jA][0], r[jA][1], r[jA][2], r[jA][3], csB, snB);

#pragma unroll
    for (int jA = 0; jA < 4; ++jA)
#pragma unroll
        for (int jB = 0; jB < 4; ++jB)
            lds[swz(base + jA * QA + jB * QB)] = r[jA][jB];
}

// Fused inverse DIT pair: stage q=QA then q=4*QA, one LDS round-trip.
template<int QA>
__device__ __forceinline__ void inv_pair(float2* lds, int tid) {
    constexpr int QB = 4 * QA;
    const int G = tid / QA;
    const int u = tid % QA;
    const int base = G * (16 * QA) + u;
    float2 r[4][4];
#pragma unroll
    for (int jA = 0; jA < 4; ++jA)
#pragma unroll
        for (int jB = 0; jB < 4; ++jB)
            r[jA][jB] = lds[swz(base + jA * QA + jB * QB)];

    const float angA = 6.283185307179586f / (float)(4 * QA);
    float snA, csA;
    __sincosf(angA * (float)u, &snA, &csA);
#pragma unroll
    for (int jB = 0; jB < 4; ++jB)
        bfly_dit_w(r[0][jB], r[1][jB], r[2][jB], r[3][jB], csA, snA);

    // Stage B twiddle for row jA is W^(u + jA*QA) = W^u * e^{+2pi*i*jA/16}
    const float angB = 6.283185307179586f / (float)(4 * QB);
    float snU, csU;
    __sincosf(angB * (float)u, &snU, &csU);
#pragma unroll
    for (int jA = 0; jA < 4; ++jA) {
        float c = csU * C16[jA] - snU * S16[jA];
        float s = snU * C16[jA] + csU * S16[jA];
        bfly_dit_w(r[jA][0], r[jA][1], r[jA][2], r[jA][3], c, s);
    }

#pragma unroll
    for (int jA = 0; jA < 4; ++jA)
#pragma unroll
        for (int jB = 0; jB < 4; ++jB)
            lds[swz(base + jA * QA + jB * QB)] = r[jA][jB];
}

__global__ LB
void fftconv_kernel(const float* __restrict__ xin,
                    const float* __restrict__ hin,
                    float* __restrict__ out)
{
    __shared__ float2 lds[N_FFT];   // 128 KiB

    const int row = blockIdx.x;
    const int tid = threadIdx.x;
    const float* xr = xin + (size_t)row * L_LEN;
    const float* hr = hin + (size_t)row * L_LEN;

    // ---- load z = x + i*h, zero-pad to N ----
#pragma unroll
    for (int i = tid; i < L_LEN / 4; i += NB) {
        float4 xv = ((const float4*)xr)[i];
        float4 hv = ((const float4*)hr)[i];
        int j = i * 4;
        lds[swz(j + 0)] = make_float2(xv.x, hv.x);
        lds[swz(j + 1)] = make_float2(xv.y, hv.y);
        lds[swz(j + 2)] = make_float2(xv.z, hv.z);
        lds[swz(j + 3)] = make_float2(xv.w, hv.w);
    }
#pragma unroll
    for (int j = L_LEN + tid; j < N_FFT; j += NB)
        lds[swz(j)] = make_float2(0.f, 0.f);
    __syncthreads();

    // ---- forward: fused radix-16 passes (q = 4096&1024, 256&64, 16&4) ----
    fwd_pair<4096>(lds, tid); __syncthreads();
    fwd_pair<256>(lds, tid);  __syncthreads();
    fwd_pair<16>(lds, tid);   __syncthreads();

    // ---- combo pass: fwd q=1 + Hermitian pointwise + inv q=1, in registers ----
    // Quad at positions 4a..4a+3 (a = rev6(b)) holds bins k*4096 + b.
    // Quad b pairs with quad 4096-b; entry k pairs with partner entry 3-k.
#pragma unroll
    for (int iter = 0; iter < 2; ++iter) {
        const int p = tid + iter * NB;          // p in [0, 2048)
        if (p == 0) {
            // quad a=0 (b=0): bins {0,4096,8192,12288}
            float2 z[4];
#pragma unroll
            for (int k = 0; k < 4; ++k) z[k] = lds[swz(0 + k)];
            bfly_dif_1(z);
            z[0] = make_float2(z[0].x * z[0].y, 0.f);   // bin 0
            z[2] = make_float2(z[2].x * z[2].y, 0.f);   // bin N/2
            pointwise_pair(z[1], z[3]);                 // 4096 <-> 12288
            bfly_dit_1(z);
#pragma unroll
            for (int k = 0; k < 4; ++k) lds[swz(0 + k)] = z[k];
            // quad a=2 (b=2048): bins k*4096+2048; pairs (0,3),(1,2)
            float2 w[4];
#pragma unroll
            for (int k = 0; k < 4; ++k) w[k] = lds[swz(8 + k)];
            bfly_dif_1(w);
            pointwise_pair(w[0], w[3]);
            pointwise_pair(w[1], w[2]);
            bfly_dit_1(w);
#pragma unroll
            for (int k = 0; k < 4; ++k) lds[swz(8 + k)] = w[k];
        } else {
            const int aA = rev4_12(p);
            const int aB = rev4_12(4096 - p);
            float2 A[4], B[4];
#pragma unroll
            for (int k = 0; k < 4; ++k) A[k] = lds[swz(4 * aA + k)];
#pragma unroll
            for (int k = 0; k < 4; ++k) B[k] = lds[swz(4 * aB + k)];
            bfly_dif_1(A);
            bfly_dif_1(B);
            pointwise_pair(A[0], B[3]);
            pointwise_pair(A[1], B[2]);
            pointwise_pair(A[2], B[1]);
            pointwise_pair(A[3], B[0]);
            bfly_dit_1(A);
            bfly_dit_1(B);
#pragma unroll
            for (int k = 0; k < 4; ++k) lds[swz(4 * aA + k)] = A[k];
#pragma unroll
            for (int k = 0; k < 4; ++k) lds[swz(4 * aB + k)] = B[k];
        }
    }
    __syncthreads();

    // ---- inverse: fused radix-16 passes (q = 4&16, 64&256, 1024&4096) ----
    inv_pair<4>(lds, tid);    __syncthreads();
    inv_pair<64>(lds, tid);   __syncthreads();
    inv_pair<1024>(lds, tid); __syncthreads();

    // ---- store first L real parts, scaled by 1/N^2 (net torch-forward 1/n) ----
    const float scale = 1.0f / ((float)N_FFT * (float)N_FFT);   // 2^-28
    float* orow = out + (size_t)row * L_LEN;
#pragma unroll
    for (int i = tid; i < L_LEN / 4; i += NB) {
        int j = 4 * i;
        float4 o;
        o.x = lds[swz(j + 0)].x * scale;
        o.y = lds[swz(j + 1)].x * scale;
        o.z = lds[swz(j + 2)].x * scale;
        o.w = lds[swz(j + 3)].x * scale;
        ((float4*)orow)[i] = o;
    }
}

extern "C" void kernel_launch(void* const* d_in, const int* in_sizes, int n_in,
                              void* d_out, int out_size, void* d_ws, size_t ws_size,
                              hipStream_t stream) {
    const float* x = (const float*)d_in[0];
    const float* h = (const float*)d_in[1];
    float* out = (float*)d_out;
    const int rows = in_sizes[0] / L_LEN;   // 2048
    fftconv_kernel<<<dim3(rows), dim3(NB), 0, stream>>>(x, h, out);
}